// Round 7
// baseline (186.442 us; speedup 1.0000x reference)
//
#include <hip/hip_runtime.h>
#include <float.h>

#define NPTS 8192
#define NB   4
#define COUT 64
#define CAP  112

typedef __attribute__((ext_vector_type(8))) short bf16x8;
typedef __attribute__((ext_vector_type(4))) float f32x4;

// LDS phase-overlay offsets (bytes), total 160768 <= 163840
#define PB_OFF    0        // chunk: 4096 cands x 32 B = 128 KB (screen passes)
#define CAF_OFF   0        // centers A-side 128 x 32 B (pre-pass, consumed to regs)
#define POOL_OFF  0        // u16[128][256] = 64 KB (between passes)
#define PD_OFF    0        // u64[16][128] = 16 KB (exact)
#define NB0_OFF   16384    // f32[128][41]
#define NB1_OFF   37376
#define NB2_OFF   58368
#define WF_OFF    79360    // folded weights f32[3][64][8]
#define COL_OFF   131072   // u16[128][112] = 28672
#define TAU_OFF   159744
#define CC_OFF    160256
#define SMEM_SZ   160768

// Screen on matrix cores: A = centers (16x32 bf16 hi/lo-packed), B = points.
// K-slots 0-10: hiC*hiP(3) + loC*hiP(3) + hiC*loP(3) + 1*nsh + 1*nsl; 11-15: 0;
// slots 16-31 alias 0-15 (both frags read quarter (l>>4)&1) => acc = 2*dtilde.
// Ordering-invariant doubling; tau margin 2e-3 covers ~2e-4 numeric error.
// Pool: per (lane,reg,group-of-32-frags) running max => 256 subset-maxima/row
// (same partition stats as R6's proven CAP<=112). tau: 16-step ballot bisect
// on high-16 monotone key bits. Collect: MFMA recompute + compare vs tau.
// Exact: f64 reference distances, u64 lex key -> rank (== lax.top_k order).
// Epilogue: folded BN+conv, maxpool prefix j<10/20/40, LeakyReLU after max.
__global__ __launch_bounds__(1024) void msedge_kernel(
    const float* __restrict__ x,
    const float* __restrict__ W,
    const float* __restrict__ gamma,
    const float* __restrict__ beta,
    const float* __restrict__ rmean,
    const float* __restrict__ rvar,
    float* __restrict__ out)
{
    __shared__ __align__(16) char smem[SMEM_SZ];
    const int t = threadIdx.x, w = t >> 6, lane = t & 63;
    const int blk = blockIdx.x;
    const int swz = (blk & 7) * 32 + (blk >> 3);   // bijective XCD swizzle (256)
    const int b = swz >> 6;
    const int n_base = (swz & 63) * 128;
    const float* __restrict__ xb = x + b * 3 * NPTS;

    unsigned* const ccnt = (unsigned*)(smem + CC_OFF);
    float* const taus = (float*)(smem + TAU_OFF);
    unsigned short* const col = (unsigned short*)(smem + COL_OFF);

    if (t < 128) ccnt[t] = 0;

    // ---------------- centers A-side build (t<128) ----------------
    if (t < 128) {
        const int n = n_base + t;
        const float c0 = xb[n], c1 = xb[NPTS + n], c2 = xb[2 * NPTS + n];
        const unsigned u0 = __float_as_uint(c0), u1 = __float_as_uint(c1), u2 = __float_as_uint(c2);
        const unsigned h0 = u0 >> 16, h1 = u1 >> 16, h2 = u2 >> 16;
        const unsigned lo0 = __float_as_uint(c0 - __uint_as_float(u0 & 0xFFFF0000u)) >> 16;
        const unsigned lo1 = __float_as_uint(c1 - __uint_as_float(u1 & 0xFFFF0000u)) >> 16;
        const unsigned lo2 = __float_as_uint(c2 - __uint_as_float(u2 & 0xFFFF0000u)) >> 16;
        const unsigned ONE = 0x3F80u;
        uint4* caf = (uint4*)(smem + CAF_OFF + t * 32);
        // A slots: [h0,h1, h2,l0, l1,l2, h0,h1 | h2,ONE, ONE,0, 0,0, 0,0]
        caf[0] = make_uint4(h0 | (h1 << 16), h2 | (lo0 << 16), lo1 | (lo2 << 16), h0 | (h1 << 16));
        caf[1] = make_uint4(h2 | (ONE << 16), ONE, 0u, 0u);
    }
    __syncthreads();

    // ---------------- A-frag to registers ----------------
    const int rt = w >> 1, half = w & 1;
    const int rbase = rt * 16 + (lane >> 4) * 4;   // + reg j -> block-row (C/D map)
    const bf16x8 afrag = *(const bf16x8*)(smem + CAF_OFF + (rt * 16 + (lane & 15)) * 32 + ((lane >> 4) & 1) * 16);
    __syncthreads();   // afrag consumed; [0,128K) free for chunks

    const int bb = (lane & 15) * 32 + ((lane >> 4) & 1) * 16;
    const f32x4 zero4 = {0.f, 0.f, 0.f, 0.f};

    // B-side staging: cand cl of current chunk (32 B), slots per audit above
    auto stage_one = [&](int cl, int m) {
        const float p0 = xb[m], p1 = xb[NPTS + m], p2 = xb[2 * NPTS + m];
        const unsigned u0 = __float_as_uint(p0), u1 = __float_as_uint(p1), u2 = __float_as_uint(p2);
        const unsigned h0 = u0 >> 16, h1 = u1 >> 16, h2 = u2 >> 16;
        const unsigned l0 = __float_as_uint(p0 - __uint_as_float(u0 & 0xFFFF0000u)) >> 16;
        const unsigned l1 = __float_as_uint(p1 - __uint_as_float(u1 & 0xFFFF0000u)) >> 16;
        const unsigned l2 = __float_as_uint(p2 - __uint_as_float(u2 & 0xFFFF0000u)) >> 16;
        const float ns = -0.5f * fmaf(p2, p2, fmaf(p1, p1, p0 * p0));
        const unsigned un = __float_as_uint(ns);
        const unsigned nh = un >> 16;
        const unsigned nl = __float_as_uint(ns - __uint_as_float(un & 0xFFFF0000u)) >> 16;
        uint4* dst = (uint4*)(smem + PB_OFF + cl * 32);
        // B slots: [h0,h1, h2,h0, h1,h2, l0,l1 | l2,nh, nl,0, 0,0, 0,0]
        dst[0] = make_uint4(h0 | (h1 << 16), h2 | (h0 << 16), h1 | (h2 << 16), l0 | (l1 << 16));
        dst[1] = make_uint4(l2 | (nh << 16), nl, 0u, 0u);
    };

    // ================= PASS 1: screen (subset maxima) =================
    f32x4 mg[8];
#pragma unroll
    for (int i = 0; i < 8; ++i) mg[i] = {-FLT_MAX, -FLT_MAX, -FLT_MAX, -FLT_MAX};

#pragma unroll
    for (int ch = 0; ch < 2; ++ch) {
#pragma unroll
        for (int k4 = 0; k4 < 4; ++k4) {
            const int cl = t + (k4 << 10);
            stage_one(cl, (ch << 12) + cl);
        }
        __syncthreads();
#pragma unroll
        for (int g2 = 0; g2 < 4; ++g2) {
            for (int ff = 0; ff < 32; ++ff) {
                const int ct = ((g2 << 5) + ff) * 2 + half;
                const bf16x8 bfrag = *(const bf16x8*)(smem + PB_OFF + ct * 512 + bb);
                const f32x4 acc = __builtin_amdgcn_mfma_f32_16x16x32_bf16(afrag, bfrag, zero4, 0, 0, 0);
                mg[ch * 4 + g2][0] = fmaxf(mg[ch * 4 + g2][0], acc[0]);
                mg[ch * 4 + g2][1] = fmaxf(mg[ch * 4 + g2][1], acc[1]);
                mg[ch * 4 + g2][2] = fmaxf(mg[ch * 4 + g2][2], acc[2]);
                mg[ch * 4 + g2][3] = fmaxf(mg[ch * 4 + g2][3], acc[3]);
            }
        }
        __syncthreads();
    }

    // ---------------- pool write (u16 keys, 256/row) ----------------
    auto key16 = [](float f) -> unsigned {
        const unsigned u = __float_as_uint(f);
        return (((int)u < 0) ? ~u : (u | 0x80000000u)) >> 16;
    };
    {
        unsigned short* pool = (unsigned short*)(smem + POOL_OFF);
#pragma unroll
        for (int j = 0; j < 4; ++j) {
            unsigned* pw = (unsigned*)(pool + (rbase + j) * 256 + half * 128 + (lane & 15) * 8);
#pragma unroll
            for (int g2 = 0; g2 < 4; ++g2)
                pw[g2] = key16(mg[2 * g2][j]) | (key16(mg[2 * g2 + 1][j]) << 16);
        }
    }
    __syncthreads();

    // ---------------- tau: per-row ballot bisect (high-16 key bits) ----------
    for (int r = 0; r < 8; ++r) {
        const int row = (w << 3) + r;
        const uint2 kk = *(const uint2*)(smem + POOL_OFF + row * 512 + lane * 8);
        const unsigned v0 = kk.x & 0xFFFFu, v1 = kk.x >> 16;
        const unsigned v2 = kk.y & 0xFFFFu, v3 = kk.y >> 16;
        unsigned lo = 0;
#pragma unroll
        for (int sb = 15; sb >= 0; --sb) {
            const unsigned c16 = lo | (1u << sb);
            const int cnt = __popcll(__ballot(v0 >= c16)) + __popcll(__ballot(v1 >= c16))
                          + __popcll(__ballot(v2 >= c16)) + __popcll(__ballot(v3 >= c16));
            if (cnt >= 40) lo = c16;
        }
        if (lane == 0) {
            const unsigned tu = lo << 16;
            const unsigned ue = (tu & 0x80000000u) ? (tu & 0x7fffffffu) : ~tu;
            taus[row] = __uint_as_float(ue) - 2e-3f;   // doubled-space margin
        }
    }
    __syncthreads();

    float tauf[4];
#pragma unroll
    for (int j = 0; j < 4; ++j) tauf[j] = taus[rbase + j];

    // ================= PASS 2: collect superset =================
    for (int ch = 0; ch < 2; ++ch) {
#pragma unroll
        for (int k4 = 0; k4 < 4; ++k4) {
            const int cl = t + (k4 << 10);
            stage_one(cl, (ch << 12) + cl);
        }
        __syncthreads();
        for (int f = 0; f < 128; ++f) {
            const int ct = f * 2 + half;
            const bf16x8 bfrag = *(const bf16x8*)(smem + PB_OFF + ct * 512 + bb);
            const f32x4 acc = __builtin_amdgcn_mfma_f32_16x16x32_bf16(afrag, bfrag, zero4, 0, 0, 0);
            const int mb = (ch << 12) + ct * 16 + (lane & 15);
#pragma unroll
            for (int j = 0; j < 4; ++j) {
                if (acc[j] >= tauf[j]) {
                    const int row = rbase + j;
                    const unsigned p = atomicAdd(&ccnt[row], 1u);
                    if (p < CAP) col[row * CAP + p] = (unsigned short)mb;
                }
            }
        }
        __syncthreads();
    }

    // ---------------- folded-weight table (overlaps exact phase) ----------
    float* const wf = (float*)(smem + WF_OFF);
    if (t < 3 * COUT) {
        const int s = t >> 6, o = t & 63, go = s * COUT + o;
        const float* Wp = W + go * 6;
        const float inv = gamma[go] / sqrtf(rvar[go] + 1e-5f);
        const float sh  = beta[go] - rmean[go] * inv;
        float* d = wf + go * 8;
        d[0] = Wp[0] * inv; d[1] = Wp[1] * inv; d[2] = Wp[2] * inv;
        d[3] = (Wp[3] - Wp[0]) * inv; d[4] = (Wp[4] - Wp[1]) * inv; d[5] = (Wp[5] - Wp[2]) * inv;
        d[6] = sh; d[7] = 0.f;
    }

    // ---------------- exact f64 + u64-key rank (8 rows/wave) ----------------
    unsigned long long* const pdw = (unsigned long long*)(smem + PD_OFF) + (size_t)w * 128;
    float* const nb0 = (float*)(smem + NB0_OFF);
    float* const nb1 = (float*)(smem + NB1_OFF);
    float* const nb2 = (float*)(smem + NB2_OFF);

#pragma unroll 1
    for (int r = 0; r < 8; ++r) {
        const int row = (w << 3) + r;
        const int n = n_base + row;
        const double D0 = (double)xb[n], D1 = (double)xb[NPTS + n], D2 = (double)xb[2 * NPTS + n];
        const double dcxx = fma(D0, D0, fma(D1, D1, D2 * D2));
        const int C = min((int)ccnt[row], CAP);
        unsigned long long mykey[2]; float e0[2], e1[2], e2[2]; bool val[2];
#pragma unroll
        for (int q = 0; q < 2; ++q) {
            const int i = lane + (q << 6);
            val[q] = (i < C); mykey[q] = 0ull;
            if (val[q]) {
                const int m = col[row * CAP + i];
                const float p0 = xb[m], p1 = xb[NPTS + m], p2 = xb[2 * NPTS + m];
                e0[q] = p0; e1[q] = p1; e2[q] = p2;
                const double P0 = p0, P1 = p1, P2 = p2;
                const double inner = fma(D0, P0, fma(D1, P1, D2 * P2));
                const double xxm   = fma(P0, P0, fma(P1, P1, P2 * P2));
                const double dd    = 2.0 * inner - dcxx - xxm;
                const unsigned long long bl = (unsigned long long)__double_as_longlong(dd);
                const unsigned long long tt =
                    bl ^ ((unsigned long long)(((long long)bl) >> 63) | 0x8000000000000000ull);
                mykey[q] = (tt & ~8191ull) | (unsigned long long)(8191 - m);
                pdw[i] = mykey[q];
            }
        }
        if ((C & 1) && lane == 0) pdw[C] = 0ull;
        asm volatile("s_waitcnt lgkmcnt(0)" ::: "memory");
        int rk0 = 0, rk1 = 0;
        for (int j2 = 0; j2 < C; j2 += 2) {
            const ulonglong2 kk2 = *(const ulonglong2*)&pdw[j2];
            rk0 += (kk2.x > mykey[0]) + (kk2.y > mykey[0]);
            rk1 += (kk2.x > mykey[1]) + (kk2.y > mykey[1]);
        }
        if (val[0] && rk0 < 40) { nb0[row * 41 + rk0] = e0[0]; nb1[row * 41 + rk0] = e1[0]; nb2[row * 41 + rk0] = e2[0]; }
        if (val[1] && rk1 < 40) { nb0[row * 41 + rk1] = e0[1]; nb1[row * 41 + rk1] = e1[1]; nb2[row * 41 + rk1] = e2[1]; }
        asm volatile("s_waitcnt lgkmcnt(0)" ::: "memory");
    }
    __syncthreads();

    // ---------------- fused conv + BN + maxpool + LeakyReLU ----------------
    const int rr = t & 127, cg = t >> 7;     // 8 threads/row, 8 channels each
    const int nn = n_base + rr;
    const float cc0 = xb[nn], cc1 = xb[NPTS + nn], cc2 = xb[2 * NPTS + nn];
#pragma unroll
    for (int s = 0; s < 3; ++s) {
        float A0[8], A1[8], A2[8], Kk[8], mx[8];
#pragma unroll
        for (int k = 0; k < 8; ++k) {
            const float* d = wf + (s * COUT + cg * 8 + k) * 8;
            A0[k] = d[0]; A1[k] = d[1]; A2[k] = d[2];
            Kk[k] = fmaf(d[3], cc0, fmaf(d[4], cc1, fmaf(d[5], cc2, d[6])));
            mx[k] = -FLT_MAX;
        }
        const int ks = (s == 0) ? 10 : (s == 1) ? 20 : 40;
        for (int j = 0; j < ks; ++j) {
            const float v0 = nb0[rr * 41 + j], v1 = nb1[rr * 41 + j], v2 = nb2[rr * 41 + j];
#pragma unroll
            for (int k = 0; k < 8; ++k)
                mx[k] = fmaxf(mx[k], fmaf(A0[k], v0, fmaf(A1[k], v1, fmaf(A2[k], v2, Kk[k]))));
        }
#pragma unroll
        for (int k = 0; k < 8; ++k) {
            const float m = mx[k];
            out[((s * NB + b) * COUT + cg * 8 + k) * NPTS + nn] = fmaxf(m, 0.2f * m);
        }
    }
}

extern "C" void kernel_launch(void* const* d_in, const int* in_sizes, int n_in,
                              void* d_out, int out_size, void* d_ws, size_t ws_size,
                              hipStream_t stream) {
    const float* x     = (const float*)d_in[0];
    const float* W     = (const float*)d_in[1];
    const float* gamma = (const float*)d_in[2];
    const float* beta  = (const float*)d_in[3];
    const float* rmean = (const float*)d_in[4];
    const float* rvar  = (const float*)d_in[5];
    float* out = (float*)d_out;

    msedge_kernel<<<dim3(NB * NPTS / 128), dim3(1024), 0, stream>>>(
        x, W, gamma, beta, rmean, rvar, out);
}